// Round 1
// baseline (635.720 us; speedup 1.0000x reference)
//
#include <hip/hip_runtime.h>

// Elementwise DeepPoly ReLU relaxation.
// Shape (8, 2048, 2048) fp32 -> N = 33,554,432 elements per tensor.
// d_out = [x_out | low_out | high_out], each N floats.
// Memory-bound streaming kernel: float4 loads/stores, 1 float4/thread.

static constexpr int N_ELEM = 8 * 2048 * 2048;   // 33554432, divisible by 4
static constexpr int N4     = N_ELEM / 4;        // 8388608 float4s

__device__ __forceinline__ void relax1(float l, float h, float& lo, float& ho) {
    const bool crossing = (l < 0.0f) & (h > 0.0f);
    const bool nonpos   = (h <= 0.0f);
    // Safe denominator: only meaningful where crossing (there h - l > 0).
    const float denom    = crossing ? (h - l) : 1.0f;
    const float ub_slope = h / denom;
    const float ub_int   = -(l * h) / denom;
    const float hc       = ub_slope * h + ub_int;
    const float lam      = (l * l > h * h) ? 0.0f : 1.0f;
    const float lc       = lam * l;
    ho = crossing ? hc : (nonpos ? 0.0f : h);
    lo = crossing ? lc : (nonpos ? 0.0f : l);
}

__global__ __launch_bounds__(256) void abstract_relu_kernel(
    const float4* __restrict__ x,
    const float4* __restrict__ low,
    const float4* __restrict__ high,
    float4* __restrict__ out_x,
    float4* __restrict__ out_low,
    float4* __restrict__ out_high)
{
    const int i = blockIdx.x * blockDim.x + threadIdx.x;
    if (i >= N4) return;

    const float4 xv = x[i];
    const float4 lv = low[i];
    const float4 hv = high[i];

    float4 rx, rl, rh;
    rx.x = fmaxf(xv.x, 0.0f);
    rx.y = fmaxf(xv.y, 0.0f);
    rx.z = fmaxf(xv.z, 0.0f);
    rx.w = fmaxf(xv.w, 0.0f);

    relax1(lv.x, hv.x, rl.x, rh.x);
    relax1(lv.y, hv.y, rl.y, rh.y);
    relax1(lv.z, hv.z, rl.z, rh.z);
    relax1(lv.w, hv.w, rl.w, rh.w);

    out_x[i]    = rx;
    out_low[i]  = rl;
    out_high[i] = rh;
}

extern "C" void kernel_launch(void* const* d_in, const int* in_sizes, int n_in,
                              void* d_out, int out_size, void* d_ws, size_t ws_size,
                              hipStream_t stream) {
    const float4* x    = (const float4*)d_in[0];
    const float4* low  = (const float4*)d_in[1];
    const float4* high = (const float4*)d_in[2];

    float* out = (float*)d_out;
    float4* out_x    = (float4*)(out);
    float4* out_low  = (float4*)(out + N_ELEM);
    float4* out_high = (float4*)(out + 2 * (long long)N_ELEM);

    const int block = 256;
    const int grid  = (N4 + block - 1) / block;  // 32768 blocks
    abstract_relu_kernel<<<grid, block, 0, stream>>>(x, low, high,
                                                     out_x, out_low, out_high);
}